// Round 16
// baseline (31.137 us; speedup 1.0000x reference)
//
#include <hip/hip_runtime.h>

typedef short s16x8 __attribute__((ext_vector_type(8)));
typedef float f32x4 __attribute__((ext_vector_type(4)));
typedef float f32x16 __attribute__((ext_vector_type(16)));
typedef unsigned u32x4 __attribute__((ext_vector_type(4)));

#define BB 4
#define NN 4096
#define LOG2E 1.4426950408889634f

__device__ __forceinline__ unsigned short f2bf(float f) {
    unsigned int u = __builtin_bit_cast(unsigned int, f);
    u += 0x7fff + ((u >> 16) & 1);   // RNE
    return (unsigned short)(u >> 16);
}

// pack two f32 -> bf16x2 (truncation) in one v_perm; low half = first arg
__device__ __forceinline__ unsigned pk2(float lo, float hi) {
    return __builtin_amdgcn_perm(__builtin_bit_cast(unsigned, hi),
                                 __builtin_bit_cast(unsigned, lo), 0x07060302u);
}

// swap lanes[32:63] of a with lanes[0:31] of b
__device__ __forceinline__ void pl32swap(unsigned &a, unsigned &b) {
    asm volatile("v_permlane32_swap_b32 %0, %1" : "+v"(a), "+v"(b));
}

// ---------------------------------------------------------------------------
// Projection via MFMA (unchanged). W packed as 80 rows (q 0-7 pre-scaled by
// log2e, k 8-15, v 16-79). Outputs (bf16): Qw,Kw [b][n][16] (k 8..15 = 0);
// Vc chunked [b][j=n>>3][c][n&7] for coalesced PV fragment loads.
// ---------------------------------------------------------------------------
__global__ __launch_bounds__(256) void proj_kernel(
    const float* __restrict__ x,
    const float* __restrict__ Wq, const float* __restrict__ bq,
    const float* __restrict__ Wk, const float* __restrict__ bk,
    const float* __restrict__ Wv, const float* __restrict__ bv,
    unsigned short* __restrict__ Qw, unsigned short* __restrict__ Kw,
    unsigned short* __restrict__ Vc)
{
    __shared__ __attribute__((aligned(16))) unsigned short sW[80 * 72];
    __shared__ __attribute__((aligned(16))) unsigned short xT[64 * 72]; // reused as sV
    __shared__ float sb[80];

    int tid = threadIdx.x;
    int b  = blockIdx.x >> 6;
    int n0 = (blockIdx.x & 63) << 6;

    for (int i = tid; i < 1280; i += 256) {
        int o = i >> 4, c4 = (i & 15) << 2;
        const float* src = (o < 8) ? &Wq[o * 64 + c4]
                         : ((o < 16) ? &Wk[(o - 8) * 64 + c4]
                                     : &Wv[(o - 16) * 64 + c4]);
        float4 v = *(const float4*)src;
        float sc = (o < 8) ? LOG2E : 1.f;
        sW[o * 72 + c4 + 0] = f2bf(v.x * sc);
        sW[o * 72 + c4 + 1] = f2bf(v.y * sc);
        sW[o * 72 + c4 + 2] = f2bf(v.z * sc);
        sW[o * 72 + c4 + 3] = f2bf(v.w * sc);
    }
    if (tid < 80)
        sb[tid] = (tid < 8) ? bq[tid] * LOG2E
                            : ((tid < 16) ? bk[tid - 8] : bv[tid - 16]);
    for (int i = tid; i < 1024; i += 256) {
        int c = i >> 4, p4 = (i & 15) << 2;
        float4 v = *(const float4*)&x[(((size_t)b * 64 + c) << 12) + n0 + p4];
        xT[(p4 + 0) * 72 + c] = f2bf(v.x);
        xT[(p4 + 1) * 72 + c] = f2bf(v.y);
        xT[(p4 + 2) * 72 + c] = f2bf(v.z);
        xT[(p4 + 3) * 72 + c] = f2bf(v.w);
    }
    __syncthreads();

    int w = tid >> 6, l = tid & 63, g = l >> 4, q16 = l & 15;
    int pix = w * 16 + q16;

    s16x8 bf0 = *(const s16x8*)&xT[pix * 72 + g * 8];
    s16x8 bf1 = *(const s16x8*)&xT[pix * 72 + 32 + g * 8];

    s16x8 a0[5], a1[5];
#pragma unroll
    for (int ot = 0; ot < 5; ++ot) {
        a0[ot] = *(const s16x8*)&sW[(ot * 16 + q16) * 72 + g * 8];
        a1[ot] = *(const s16x8*)&sW[(ot * 16 + q16) * 72 + 32 + g * 8];
    }
    __syncthreads();   // xT frags consumed; recycle as sV

    unsigned short* sV = xT;
    size_t base16 = ((size_t)(b << 12) + n0 + pix) << 4;

#pragma unroll
    for (int ot = 0; ot < 5; ++ot) {
        f32x4 acc = {0.f, 0.f, 0.f, 0.f};
        acc = __builtin_amdgcn_mfma_f32_16x16x32_bf16(a0[ot], bf0, acc, 0, 0, 0);
        acc = __builtin_amdgcn_mfma_f32_16x16x32_bf16(a1[ot], bf1, acc, 0, 0, 0);
#pragma unroll
        for (int r = 0; r < 4; ++r) {
            int orow = ot * 16 + g * 4 + r;
            unsigned short hv = f2bf(acc[r] + sb[orow]);
            if (ot == 0) {
                if (orow < 8) {
                    Qw[base16 + orow] = hv;
                    Qw[base16 + orow + 8] = 0;
                } else {
                    Kw[base16 + orow - 8] = hv;
                    Kw[base16 + orow] = 0;
                }
            } else {
                sV[(orow - 16) * 72 + pix] = hv;
            }
        }
    }
    __syncthreads();

    // chunked V stores: Vc[b][j][c][8], 16B per (j,c)
#pragma unroll
    for (int i = tid; i < 512; i += 256) {
        int jj = i >> 6, c = i & 63;
        u32x4 v = *(const u32x4*)&sV[c * 72 + jj * 8];
        int jglob = ((blockIdx.x & 63) << 3) + jj;
        *(u32x4*)&Vc[(((size_t)b * 512 + jglob) * 64 + c) * 8] = v;
    }
}

// ---------------------------------------------------------------------------
// Warmer: pulls each batch's Q/K/V into the L2s of the XCDs whose attn
// blocks will read them (same blockIdx&7 keying as attn). 512 blocks; the
// 64 blocks sharing one XCD key cooperatively read their batch's full
// 1.5 MB (12 KB/block, 3 x 16B per thread). Loads kept live by a
// data-dependent, (almost surely) never-taken store into ws scratch.
// ---------------------------------------------------------------------------
__global__ __launch_bounds__(256) void warm_kernel(
    const char* __restrict__ wsbase, unsigned* __restrict__ sink)
{
    int p = blockIdx.x;
    int xcd = p & 7, b = xcd >> 1, j = p >> 3;   // j in 0..63
    int tid = threadIdx.x;

    const char* Qs = wsbase + (size_t)b * 131072 + j * 2048;            // 2 KB
    const char* Ks = wsbase + 524288 + (size_t)b * 131072 + j * 2048;   // 2 KB
    const char* Vs = wsbase + 1048576 + (size_t)b * 524288 + j * 8192;  // 8 KB

    const char* qk = (tid < 128) ? (Qs + tid * 16) : (Ks + (tid - 128) * 16);
    u32x4 a  = *(const u32x4*)qk;
    u32x4 v0 = *(const u32x4*)(Vs + tid * 16);
    u32x4 v1 = *(const u32x4*)(Vs + 4096 + tid * 16);
    u32x4 s = a ^ v0 ^ v1;
    unsigned v = s[0] ^ s[1] ^ s[2] ^ s[3];
    if (v == 0x13572468u) sink[p * 256 + tid] = v;   // keeps loads live; ~never fires
}

// ---------------------------------------------------------------------------
// Flash attention (R13 byte-identical). 32x32x16 MFMA, in-register P, no
// LDS/barriers in main loop; V from L2 in chunked layout; rotating 1-ahead
// register prefetch. Block = 512 thr = 8 waves = 32 q x 8-way key split.
// ---------------------------------------------------------------------------
template <int REPS>
__global__ __launch_bounds__(512, 2) void attn_t(
    const unsigned short* __restrict__ Qw, const unsigned short* __restrict__ Kw,
    const unsigned short* __restrict__ Vc, const float* __restrict__ x,
    const float* __restrict__ gamma, float* __restrict__ outp)
{
    __shared__ __attribute__((aligned(16))) float sO[64 * 36];
    __shared__ float sL[8 * 32];
    __shared__ float sGL[32];

    int tid = threadIdx.x;
    int w = tid >> 6, l = tid & 63, r31 = l & 31, hi = l >> 5;
    // XCD-aware remap: xcd = blockIdx%8 serves batch xcd>>1 (K/Q/V L2-resident)
    int p = blockIdx.x;
    int xcd = p & 7, kgrp = p >> 3;
    int b = xcd >> 1;
    int n0 = (((kgrp << 1) | (xcd & 1))) << 5;
    float gm = gamma[0];

    // Q fragment (32 queries of this block)
    s16x8 qf = *(const s16x8*)((const char*)Qw + ((size_t)b << 17)
                               + ((size_t)(n0 + r31) << 5) + (hi << 4));
    // K: wave w's 512-key slice; per chunk +ch*1024B
    const char* KbW = (const char*)Kw + ((size_t)b << 17) + (w << 14)
                    + (r31 << 5) + (hi << 4);
    // V chunked: wave w's slice; per chunk +ch*4096B; A1 +2048, B0 +512, B1 +2560
    const char* VcB = (const char*)Vc + ((size_t)b << 19) + (w << 16)
                    + (hi << 10) + (r31 << 4);

    f32x16 zz;
#pragma unroll
    for (int i = 0; i < 16; ++i) zz[i] = 0.f;

    for (int rep = 0; rep < REPS; ++rep) {
        f32x16 acc0, acc1;
#pragma unroll
        for (int i = 0; i < 16; ++i) { acc0[i] = 0.f; acc1[i] = 0.f; }
        float la = 0.f;

        s16x8 cK  = *(const s16x8*)(KbW);
        s16x8 cA0 = *(const s16x8*)(VcB);
        s16x8 cA1 = *(const s16x8*)(VcB + 2048);
        s16x8 cB0 = *(const s16x8*)(VcB + 512);
        s16x8 cB1 = *(const s16x8*)(VcB + 2560);

#pragma unroll
        for (int ch = 0; ch < 16; ++ch) {
            // prefetch chunk ch+1 (used next iteration)
            s16x8 nK = cK, nA0 = cA0, nA1 = cA1, nB0 = cB0, nB1 = cB1;
            if (ch < 15) {
                const char* pk = KbW + ((ch + 1) << 10);
                const char* pv = VcB + ((ch + 1) << 12);
                nK  = *(const s16x8*)(pk);
                nA0 = *(const s16x8*)(pv);
                nA1 = *(const s16x8*)(pv + 2048);
                nB0 = *(const s16x8*)(pv + 512);
                nB1 = *(const s16x8*)(pv + 2560);
            }

            f32x16 E = __builtin_amdgcn_mfma_f32_32x32x16_bf16(cK, qf, zz, 0, 0, 0);
#pragma unroll
            for (int i = 0; i < 16; ++i) E[i] = __builtin_amdgcn_exp2f(E[i]);
            la += (((E[0] + E[1]) + (E[2] + E[3])) + ((E[4] + E[5]) + (E[6] + E[7])))
                + (((E[8] + E[9]) + (E[10] + E[11])) + ((E[12] + E[13]) + (E[14] + E[15])));

            unsigned x0 = pk2(E[0], E[1]),   x1 = pk2(E[2], E[3]);
            unsigned x2 = pk2(E[4], E[5]),   x3 = pk2(E[6], E[7]);
            unsigned x4 = pk2(E[8], E[9]),   x5 = pk2(E[10], E[11]);
            unsigned x6 = pk2(E[12], E[13]), x7 = pk2(E[14], E[15]);
            pl32swap(x0, x2); pl32swap(x1, x3);
            pl32swap(x4, x6); pl32swap(x5, x7);
            u32x4 u0 = {x0, x1, x2, x3}, u1 = {x4, x5, x6, x7};
            s16x8 pf0 = __builtin_bit_cast(s16x8, u0);
            s16x8 pf1 = __builtin_bit_cast(s16x8, u1);

            acc0 = __builtin_amdgcn_mfma_f32_32x32x16_bf16(cA0, pf0, acc0, 0, 0, 0);
            acc0 = __builtin_amdgcn_mfma_f32_32x32x16_bf16(cA1, pf1, acc0, 0, 0, 0);
            acc1 = __builtin_amdgcn_mfma_f32_32x32x16_bf16(cB0, pf0, acc1, 0, 0, 0);
            acc1 = __builtin_amdgcn_mfma_f32_32x32x16_bf16(cB1, pf1, acc1, 0, 0, 0);

            cK = nK; cA0 = nA0; cA1 = nA1; cB0 = nB0; cB1 = nB1;
        }

        // ---- denominators ----
        la += __shfl_xor(la, 32);
        if (l < 32) sL[w * 32 + l] = la;

        // ---- rotation merge into sO (8 bands x 8 channels), stride 36 ----
#pragma unroll
        for (int s = 0; s < 8; ++s) {
            __syncthreads();
#pragma unroll
            for (int B = 0; B < 8; ++B) {
                if (((w + s) & 7) == B) {
                    const int R2 = B & 3;
                    float e0 = (B < 4) ? acc0[R2 * 4 + 0] : acc1[R2 * 4 + 0];
                    float e1 = (B < 4) ? acc0[R2 * 4 + 1] : acc1[R2 * 4 + 1];
                    float e2 = (B < 4) ? acc0[R2 * 4 + 2] : acc1[R2 * 4 + 2];
                    float e3 = (B < 4) ? acc0[R2 * 4 + 3] : acc1[R2 * 4 + 3];
                    float* pp = &sO[(B * 8 + hi * 4) * 36 + r31];
                    if (s == 0) {
                        pp[0] = e0; pp[36] = e1; pp[72] = e2; pp[108] = e3;
                    } else {
                        pp[0] += e0; pp[36] += e1; pp[72] += e2; pp[108] += e3;
                    }
                }
            }
        }
        __syncthreads();

        if (tid < 32) {
            float L = 0.f;
#pragma unroll
            for (int wk2 = 0; wk2 < 8; ++wk2) L += sL[wk2 * 32 + tid];
            sGL[tid] = gm / L;
        }
        __syncthreads();

        // ---- epilogue: 512 threads x one float4 ----
        {
            int c = tid >> 3, qc = tid & 7;
            float4 o4 = *(const float4*)&sO[c * 36 + qc * 4];
            float4 g4 = *(const float4*)&sGL[qc * 4];
            size_t idx = (((size_t)b * 64 + c) << 12) + n0 + qc * 4;
            float4 x4v = *(const float4*)&x[idx];
            o4.x = o4.x * g4.x + x4v.x;
            o4.y = o4.y * g4.y + x4v.y;
            o4.z = o4.z * g4.z + x4v.z;
            o4.w = o4.w * g4.w + x4v.w;
            *(float4*)&outp[idx] = o4;
        }
        if (REPS > 1) __syncthreads();
    }
}

extern "C" void kernel_launch(void* const* d_in, const int* in_sizes, int n_in,
                              void* d_out, int out_size, void* d_ws, size_t ws_size,
                              hipStream_t stream) {
    const float* x     = (const float*)d_in[0];
    const float* Wq    = (const float*)d_in[1];
    const float* bq    = (const float*)d_in[2];
    const float* Wk    = (const float*)d_in[3];
    const float* bk    = (const float*)d_in[4];
    const float* Wv    = (const float*)d_in[5];
    const float* bv    = (const float*)d_in[6];
    const float* gamma = (const float*)d_in[7];
    float* out = (float*)d_out;

    unsigned short* Qw = (unsigned short*)d_ws;          // [B][N][16] bf16 (padded)
    unsigned short* Kw = Qw + (size_t)BB * NN * 16;      // [B][N][16] bf16 (padded)
    unsigned short* Vc = Kw + (size_t)BB * NN * 16;      // [B][N/8][C][8] bf16
    unsigned* sink = (unsigned*)((char*)d_ws + (size_t)(16 << 20));

    proj_kernel<<<256, 256, 0, stream>>>(x, Wq, bq, Wk, bk, Wv, bv, Qw, Kw, Vc);
    warm_kernel<<<512, 256, 0, stream>>>((const char*)d_ws, sink);
    attn_t<1><<<512, 512, 0, stream>>>(Qw, Kw, Vc, x, gamma, out);
}

// Round 17
// 29.305 us; speedup vs baseline: 1.0625x; 1.0625x over previous
//
#include <hip/hip_runtime.h>

typedef short s16x8 __attribute__((ext_vector_type(8)));
typedef float f32x4 __attribute__((ext_vector_type(4)));
typedef float f32x16 __attribute__((ext_vector_type(16)));
typedef unsigned u32x4 __attribute__((ext_vector_type(4)));

#define BB 4
#define NN 4096
#define LOG2E 1.4426950408889634f

__device__ __forceinline__ unsigned short f2bf(float f) {
    unsigned int u = __builtin_bit_cast(unsigned int, f);
    u += 0x7fff + ((u >> 16) & 1);   // RNE
    return (unsigned short)(u >> 16);
}

// pack two f32 -> bf16x2 (truncation) in one v_perm; low half = first arg
__device__ __forceinline__ unsigned pk2(float lo, float hi) {
    return __builtin_amdgcn_perm(__builtin_bit_cast(unsigned, hi),
                                 __builtin_bit_cast(unsigned, lo), 0x07060302u);
}

// swap lanes[32:63] of a with lanes[0:31] of b
__device__ __forceinline__ void pl32swap(unsigned &a, unsigned &b) {
    asm volatile("v_permlane32_swap_b32 %0, %1" : "+v"(a), "+v"(b));
}

// ---------------------------------------------------------------------------
// Projection via MFMA. R17: blocks XCD-keyed like attn (xcd=blockIdx&7 ->
// batch xcd>>1), so each batch's Q/K/V lines are written into the L2s of
// the XCDs whose attn blocks read them. W packed as 80 rows (q 0-7
// pre-scaled by log2e, k 8-15, v 16-79). Outputs (bf16): Qw,Kw [b][n][16]
// (k 8..15 = 0); Vc chunked [b][j=n>>3][c][n&7].
// ---------------------------------------------------------------------------
__global__ __launch_bounds__(256) void proj_kernel(
    const float* __restrict__ x,
    const float* __restrict__ Wq, const float* __restrict__ bq,
    const float* __restrict__ Wk, const float* __restrict__ bk,
    const float* __restrict__ Wv, const float* __restrict__ bv,
    unsigned short* __restrict__ Qw, unsigned short* __restrict__ Kw,
    unsigned short* __restrict__ Vc)
{
    __shared__ __attribute__((aligned(16))) unsigned short sW[80 * 72];
    __shared__ __attribute__((aligned(16))) unsigned short xT[64 * 72]; // reused as sV
    __shared__ float sb[80];

    int tid = threadIdx.x;
    int p   = blockIdx.x;
    int xcd = p & 7;
    int b   = xcd >> 1;                              // batch served by this XCD pair
    int nb  = ((p >> 3) << 1) | (xcd & 1);           // 64-pixel block index, 0..63
    int n0  = nb << 6;

    for (int i = tid; i < 1280; i += 256) {
        int o = i >> 4, c4 = (i & 15) << 2;
        const float* src = (o < 8) ? &Wq[o * 64 + c4]
                         : ((o < 16) ? &Wk[(o - 8) * 64 + c4]
                                     : &Wv[(o - 16) * 64 + c4]);
        float4 v = *(const float4*)src;
        float sc = (o < 8) ? LOG2E : 1.f;
        sW[o * 72 + c4 + 0] = f2bf(v.x * sc);
        sW[o * 72 + c4 + 1] = f2bf(v.y * sc);
        sW[o * 72 + c4 + 2] = f2bf(v.z * sc);
        sW[o * 72 + c4 + 3] = f2bf(v.w * sc);
    }
    if (tid < 80)
        sb[tid] = (tid < 8) ? bq[tid] * LOG2E
                            : ((tid < 16) ? bk[tid - 8] : bv[tid - 16]);
    for (int i = tid; i < 1024; i += 256) {
        int c = i >> 4, p4 = (i & 15) << 2;
        float4 v = *(const float4*)&x[(((size_t)b * 64 + c) << 12) + n0 + p4];
        xT[(p4 + 0) * 72 + c] = f2bf(v.x);
        xT[(p4 + 1) * 72 + c] = f2bf(v.y);
        xT[(p4 + 2) * 72 + c] = f2bf(v.z);
        xT[(p4 + 3) * 72 + c] = f2bf(v.w);
    }
    __syncthreads();

    int w = tid >> 6, l = tid & 63, g = l >> 4, q16 = l & 15;
    int pix = w * 16 + q16;

    s16x8 bf0 = *(const s16x8*)&xT[pix * 72 + g * 8];
    s16x8 bf1 = *(const s16x8*)&xT[pix * 72 + 32 + g * 8];

    s16x8 a0[5], a1[5];
#pragma unroll
    for (int ot = 0; ot < 5; ++ot) {
        a0[ot] = *(const s16x8*)&sW[(ot * 16 + q16) * 72 + g * 8];
        a1[ot] = *(const s16x8*)&sW[(ot * 16 + q16) * 72 + 32 + g * 8];
    }
    __syncthreads();   // xT frags consumed; recycle as sV

    unsigned short* sV = xT;
    size_t base16 = ((size_t)(b << 12) + n0 + pix) << 4;

#pragma unroll
    for (int ot = 0; ot < 5; ++ot) {
        f32x4 acc = {0.f, 0.f, 0.f, 0.f};
        acc = __builtin_amdgcn_mfma_f32_16x16x32_bf16(a0[ot], bf0, acc, 0, 0, 0);
        acc = __builtin_amdgcn_mfma_f32_16x16x32_bf16(a1[ot], bf1, acc, 0, 0, 0);
#pragma unroll
        for (int r = 0; r < 4; ++r) {
            int orow = ot * 16 + g * 4 + r;
            unsigned short hv = f2bf(acc[r] + sb[orow]);
            if (ot == 0) {
                if (orow < 8) {
                    Qw[base16 + orow] = hv;
                    Qw[base16 + orow + 8] = 0;
                } else {
                    Kw[base16 + orow - 8] = hv;
                    Kw[base16 + orow] = 0;
                }
            } else {
                sV[(orow - 16) * 72 + pix] = hv;
            }
        }
    }
    __syncthreads();

    // chunked V stores: Vc[b][j][c][8], 16B per (j,c)
#pragma unroll
    for (int i = tid; i < 512; i += 256) {
        int jj = i >> 6, c = i & 63;
        u32x4 v = *(const u32x4*)&sV[c * 72 + jj * 8];
        int jglob = (nb << 3) + jj;
        *(u32x4*)&Vc[(((size_t)b * 512 + jglob) * 64 + c) * 8] = v;
    }
}

// ---------------------------------------------------------------------------
// Flash attention (R13 main loop, byte-identical math). 32x32x16 MFMA,
// in-register P, no LDS/barriers in main loop; V from L2 chunked; rotating
// 1-ahead register prefetch. Block = 512 thr = 8 waves = 32 q x 8-way key
// split. R17: n-mapping keys n/64-parity to xcd&1, matching proj's writes
// (Q/x/out reads land in the local XCD's L2).
// ---------------------------------------------------------------------------
__global__ __launch_bounds__(512, 2) void attn_kernel(
    const unsigned short* __restrict__ Qw, const unsigned short* __restrict__ Kw,
    const unsigned short* __restrict__ Vc, const float* __restrict__ x,
    const float* __restrict__ gamma, float* __restrict__ outp)
{
    __shared__ __attribute__((aligned(16))) float sO[64 * 36];
    __shared__ float sL[8 * 32];
    __shared__ float sGL[32];

    int tid = threadIdx.x;
    int w = tid >> 6, l = tid & 63, r31 = l & 31, hi = l >> 5;
    // XCD-aware remap: xcd = blockIdx&7 serves batch xcd>>1; n/64-parity
    // equals xcd&1 so Q/x/out lines were written by this XCD's proj blocks.
    int p = blockIdx.x;
    int xcd = p & 7, kgrp = p >> 3;                 // kgrp 0..63
    int b = xcd >> 1;
    int n32 = (kgrp & 1) | ((xcd & 1) << 1) | ((kgrp >> 1) << 2);  // 0..127
    int n0 = n32 << 5;
    float gm = gamma[0];

    // Q fragment (32 queries of this block)
    s16x8 qf = *(const s16x8*)((const char*)Qw + ((size_t)b << 17)
                               + ((size_t)(n0 + r31) << 5) + (hi << 4));
    // K: wave w's 512-key slice; per chunk +ch*1024B
    const char* KbW = (const char*)Kw + ((size_t)b << 17) + (w << 14)
                    + (r31 << 5) + (hi << 4);
    // V chunked: wave w's slice; per chunk +ch*4096B; A1 +2048, B0 +512, B1 +2560
    const char* VcB = (const char*)Vc + ((size_t)b << 19) + (w << 16)
                    + (hi << 10) + (r31 << 4);

    f32x16 zz;
#pragma unroll
    for (int i = 0; i < 16; ++i) zz[i] = 0.f;

    f32x16 acc0, acc1;
#pragma unroll
    for (int i = 0; i < 16; ++i) { acc0[i] = 0.f; acc1[i] = 0.f; }
    float la = 0.f;

    s16x8 cK  = *(const s16x8*)(KbW);
    s16x8 cA0 = *(const s16x8*)(VcB);
    s16x8 cA1 = *(const s16x8*)(VcB + 2048);
    s16x8 cB0 = *(const s16x8*)(VcB + 512);
    s16x8 cB1 = *(const s16x8*)(VcB + 2560);

#pragma unroll
    for (int ch = 0; ch < 16; ++ch) {
        // prefetch chunk ch+1 (used next iteration)
        s16x8 nK = cK, nA0 = cA0, nA1 = cA1, nB0 = cB0, nB1 = cB1;
        if (ch < 15) {
            const char* pk = KbW + ((ch + 1) << 10);
            const char* pv = VcB + ((ch + 1) << 12);
            nK  = *(const s16x8*)(pk);
            nA0 = *(const s16x8*)(pv);
            nA1 = *(const s16x8*)(pv + 2048);
            nB0 = *(const s16x8*)(pv + 512);
            nB1 = *(const s16x8*)(pv + 2560);
        }

        f32x16 E = __builtin_amdgcn_mfma_f32_32x32x16_bf16(cK, qf, zz, 0, 0, 0);
#pragma unroll
        for (int i = 0; i < 16; ++i) E[i] = __builtin_amdgcn_exp2f(E[i]);
        la += (((E[0] + E[1]) + (E[2] + E[3])) + ((E[4] + E[5]) + (E[6] + E[7])))
            + (((E[8] + E[9]) + (E[10] + E[11])) + ((E[12] + E[13]) + (E[14] + E[15])));

        unsigned x0 = pk2(E[0], E[1]),   x1 = pk2(E[2], E[3]);
        unsigned x2 = pk2(E[4], E[5]),   x3 = pk2(E[6], E[7]);
        unsigned x4 = pk2(E[8], E[9]),   x5 = pk2(E[10], E[11]);
        unsigned x6 = pk2(E[12], E[13]), x7 = pk2(E[14], E[15]);
        pl32swap(x0, x2); pl32swap(x1, x3);
        pl32swap(x4, x6); pl32swap(x5, x7);
        u32x4 u0 = {x0, x1, x2, x3}, u1 = {x4, x5, x6, x7};
        s16x8 pf0 = __builtin_bit_cast(s16x8, u0);
        s16x8 pf1 = __builtin_bit_cast(s16x8, u1);

        acc0 = __builtin_amdgcn_mfma_f32_32x32x16_bf16(cA0, pf0, acc0, 0, 0, 0);
        acc0 = __builtin_amdgcn_mfma_f32_32x32x16_bf16(cA1, pf1, acc0, 0, 0, 0);
        acc1 = __builtin_amdgcn_mfma_f32_32x32x16_bf16(cB0, pf0, acc1, 0, 0, 0);
        acc1 = __builtin_amdgcn_mfma_f32_32x32x16_bf16(cB1, pf1, acc1, 0, 0, 0);

        cK = nK; cA0 = nA0; cA1 = nA1; cB0 = nB0; cB1 = nB1;
    }

    // ---- denominators ----
    la += __shfl_xor(la, 32);
    if (l < 32) sL[w * 32 + l] = la;

    // ---- rotation merge into sO (8 bands x 8 channels), stride 36 ----
#pragma unroll
    for (int s = 0; s < 8; ++s) {
        __syncthreads();
#pragma unroll
        for (int B = 0; B < 8; ++B) {
            if (((w + s) & 7) == B) {
                const int R2 = B & 3;
                float e0 = (B < 4) ? acc0[R2 * 4 + 0] : acc1[R2 * 4 + 0];
                float e1 = (B < 4) ? acc0[R2 * 4 + 1] : acc1[R2 * 4 + 1];
                float e2 = (B < 4) ? acc0[R2 * 4 + 2] : acc1[R2 * 4 + 2];
                float e3 = (B < 4) ? acc0[R2 * 4 + 3] : acc1[R2 * 4 + 3];
                float* pp = &sO[(B * 8 + hi * 4) * 36 + r31];
                if (s == 0) {
                    pp[0] = e0; pp[36] = e1; pp[72] = e2; pp[108] = e3;
                } else {
                    pp[0] += e0; pp[36] += e1; pp[72] += e2; pp[108] += e3;
                }
            }
        }
    }
    __syncthreads();

    if (tid < 32) {
        float L = 0.f;
#pragma unroll
        for (int wk2 = 0; wk2 < 8; ++wk2) L += sL[wk2 * 32 + tid];
        sGL[tid] = gm / L;
    }
    __syncthreads();

    // ---- epilogue: 512 threads x one float4 ----
    {
        int c = tid >> 3, qc = tid & 7;
        float4 o4 = *(const float4*)&sO[c * 36 + qc * 4];
        float4 g4 = *(const float4*)&sGL[qc * 4];
        size_t idx = (((size_t)b * 64 + c) << 12) + n0 + qc * 4;
        float4 x4v = *(const float4*)&x[idx];
        o4.x = o4.x * g4.x + x4v.x;
        o4.y = o4.y * g4.y + x4v.y;
        o4.z = o4.z * g4.z + x4v.z;
        o4.w = o4.w * g4.w + x4v.w;
        *(float4*)&outp[idx] = o4;
    }
}

extern "C" void kernel_launch(void* const* d_in, const int* in_sizes, int n_in,
                              void* d_out, int out_size, void* d_ws, size_t ws_size,
                              hipStream_t stream) {
    const float* x     = (const float*)d_in[0];
    const float* Wq    = (const float*)d_in[1];
    const float* bq    = (const float*)d_in[2];
    const float* Wk    = (const float*)d_in[3];
    const float* bk    = (const float*)d_in[4];
    const float* Wv    = (const float*)d_in[5];
    const float* bv    = (const float*)d_in[6];
    const float* gamma = (const float*)d_in[7];
    float* out = (float*)d_out;

    unsigned short* Qw = (unsigned short*)d_ws;          // [B][N][16] bf16 (padded)
    unsigned short* Kw = Qw + (size_t)BB * NN * 16;      // [B][N][16] bf16 (padded)
    unsigned short* Vc = Kw + (size_t)BB * NN * 16;      // [B][N/8][C][8] bf16

    proj_kernel<<<256, 256, 0, stream>>>(x, Wq, bq, Wk, bk, Wv, bv, Qw, Kw, Vc);
    attn_kernel<<<512, 512, 0, stream>>>(Qw, Kw, Vc, x, gamma, out);
}